// Round 5
// baseline (1729.415 us; speedup 1.0000x reference)
//
#include <hip/hip_runtime.h>
#include <hip/hip_bf16.h>
#include <math.h>

// Problem constants
#define B_  4
#define S_  512
#define H_  768
#define NH_ 12
#define DH_ 64
#define FF_ 3072
#define L_  6
#define V_  30522
#define QKVN 2304          // fused QKV output width
#define M_  (B_ * S_)      // 2048 tokens

typedef short s16x8 __attribute__((ext_vector_type(8)));
typedef short s16x4v __attribute__((ext_vector_type(4)));
typedef float f32x4 __attribute__((ext_vector_type(4)));

__device__ __forceinline__ void gload_lds16(const void* g, void* l) {
    __builtin_amdgcn_global_load_lds(
        (const __attribute__((address_space(1))) void*)g,
        (__attribute__((address_space(3))) void*)l,
        16, 0, 0);
}

__device__ __forceinline__ ushort f2bu(float x) {
    __hip_bfloat16 h = __float2bfloat16(x);
    return *(ushort*)&h;
}

// read 8 contiguous bf16 from LDS as two 8B chunks (8B-aligned offsets only)
__device__ __forceinline__ s16x8 lds_frag(const ushort* p) {
    s16x4v lo = *(const s16x4v*)p;
    s16x4v hi = *(const s16x4v*)(p + 4);
    return __builtin_shufflevector(lo, hi, 0, 1, 2, 3, 4, 5, 6, 7);
}

// ---------------------------------------------------------------------------
// Embedding gather + LayerNorm -> x (fp32) and xb (bf16 shadow).
// ---------------------------------------------------------------------------
__global__ __launch_bounds__(256) void embed_ln_kernel(
    const int* __restrict__ ids, const int* __restrict__ tt,
    const float* __restrict__ wemb, const float* __restrict__ pemb,
    const float* __restrict__ temb, const float* __restrict__ g,
    const float* __restrict__ bb, float* __restrict__ x,
    __hip_bfloat16* __restrict__ xb)
{
    const int t = blockIdx.x;
    const int s = t % S_;
    const int tid = threadIdx.x;
    __shared__ float red[256];

    const float* wr = wemb + (size_t)ids[t] * H_;
    const float* pr = pemb + (size_t)s * H_;
    const float* tr = temb + (size_t)tt[t] * H_;

    float v[3];
    float sum = 0.f;
#pragma unroll
    for (int i = 0; i < 3; i++) {
        int c = tid + i * 256;
        v[i] = wr[c] + pr[c] + tr[c];
        sum += v[i];
    }
    red[tid] = sum; __syncthreads();
    for (int st = 128; st > 0; st >>= 1) { if (tid < st) red[tid] += red[tid + st]; __syncthreads(); }
    const float mean = red[0] / (float)H_;
    __syncthreads();
    float s2 = 0.f;
#pragma unroll
    for (int i = 0; i < 3; i++) { float d = v[i] - mean; s2 += d * d; }
    red[tid] = s2; __syncthreads();
    for (int st = 128; st > 0; st >>= 1) { if (tid < st) red[tid] += red[tid + st]; __syncthreads(); }
    const float rstd = rsqrtf(red[0] / (float)H_ + 1e-12f);
#pragma unroll
    for (int i = 0; i < 3; i++) {
        int c = tid + i * 256;
        float o = (v[i] - mean) * rstd * g[c] + bb[c];
        x[(size_t)t * H_ + c] = o;
        xb[(size_t)t * H_ + c] = __float2bfloat16(o);
    }
}

// ---------------------------------------------------------------------------
// Per-layer weight prep, ONE launch: transposes wq|wk|wv -> Wt_qkv, wo -> Wt_o,
// w1 -> Wt_1, w2 -> Wt_2 (all fp32 [K][N] -> bf16 [N][K]) + bias concat.
// ---------------------------------------------------------------------------
__device__ __forceinline__ void tr_tile(
    const float* __restrict__ src, ushort* __restrict__ dst,
    int K, int N, int t, int ncols, float (*tile)[33])
{
    const int tx = threadIdx.x, ty = threadIdx.y;
    const int n0 = (t % ncols) * 32;
    const int k0 = (t / ncols) * 32;
#pragma unroll
    for (int i = 0; i < 4; i++)
        tile[ty + 8 * i][tx] = src[(size_t)(k0 + ty + 8 * i) * N + n0 + tx];
    __syncthreads();
#pragma unroll
    for (int i = 0; i < 4; i++)
        dst[(size_t)(n0 + ty + 8 * i) * K + k0 + tx] = f2bu(tile[tx][ty + 8 * i]);
}

__global__ __launch_bounds__(256) void prep_layer_kernel(
    const float* __restrict__ wq, const float* __restrict__ wk,
    const float* __restrict__ wv, const float* __restrict__ wo,
    const float* __restrict__ w1, const float* __restrict__ w2,
    const float* __restrict__ bq, const float* __restrict__ bk,
    const float* __restrict__ bv,
    ushort* __restrict__ Wt_qkv, ushort* __restrict__ Wt_o,
    ushort* __restrict__ Wt_1, ushort* __restrict__ Wt_2,
    float* __restrict__ b_qkv)
{
    __shared__ float tile[32][33];
    const int id = blockIdx.x;
    if (id < 1728) {                      // QKV: 3 x 576 tiles of 768x768
        const int mat = id / 576, t = id % 576;
        const float* src = (mat == 0) ? wq : (mat == 1) ? wk : wv;
        tr_tile(src, Wt_qkv + (size_t)mat * H_ * H_, H_, H_, t, 24, tile);
    } else if (id < 2304) {               // O: 576 tiles
        tr_tile(wo, Wt_o, H_, H_, id - 1728, 24, tile);
    } else if (id < 4608) {               // W1: 768x3072, 2304 tiles
        tr_tile(w1, Wt_1, H_, FF_, id - 2304, 96, tile);
    } else if (id < 6912) {               // W2: 3072x768, 2304 tiles
        tr_tile(w2, Wt_2, FF_, H_, id - 4608, 24, tile);
    } else {                              // bias concat (9 blocks x 256)
        int i = (id - 6912) * 256 + threadIdx.y * 32 + threadIdx.x;
        if (i < QKVN)
            b_qkv[i] = (i < H_) ? bq[i] : ((i < 2 * H_) ? bk[i - H_] : bv[i - 2 * H_]);
    }
}

// ---------------------------------------------------------------------------
// Split-K bf16 MFMA GEMM: C[M][N] (fp32, pre-zeroed) += A @ Bt^T (+bias on
// chunk 0).  128x128 tile, BK=32 double-buffered LDS, grid.z = K-split.
// ---------------------------------------------------------------------------
#define TM 128
#define TN 128
#define TK 32

__global__ __launch_bounds__(256) void gemm_splitk_kernel(
    const ushort* __restrict__ A, const ushort* __restrict__ Bt,
    const float* __restrict__ bias, float* __restrict__ C,
    int Kfull, int N, int klen)
{
    __shared__ ushort As[2][TM * TK];
    __shared__ ushort Bs[2][TN * TK];
    const int tid  = threadIdx.x;
    const int lane = tid & 63;
    const int wave = tid >> 6;
    const int m0 = blockIdx.y * TM;
    const int n0 = blockIdx.x * TN;
    const int kbase = blockIdx.z * klen;
    const int wm = (wave >> 1) * 64;
    const int wn = (wave & 1) * 64;

    f32x4 acc[4][4];
#pragma unroll
    for (int i = 0; i < 4; i++)
#pragma unroll
        for (int j = 0; j < 4; j++)
            acc[i][j] = (f32x4){0.f, 0.f, 0.f, 0.f};

    // staging: wave w stages 1KB chunks {2w,2w+1} of A and of B per K-step
    const int c0 = wave * 2;
    const int rr = lane >> 2;
    const int ko = (lane & 3) * 8;
    const ushort* aS0 = A  + (size_t)(m0 + c0 * 16 + rr)       * Kfull + kbase + ko;
    const ushort* aS1 = A  + (size_t)(m0 + (c0 + 1) * 16 + rr) * Kfull + kbase + ko;
    const ushort* bS0 = Bt + (size_t)(n0 + c0 * 16 + rr)       * Kfull + kbase + ko;
    const ushort* bS1 = Bt + (size_t)(n0 + (c0 + 1) * 16 + rr) * Kfull + kbase + ko;
    const int aOff0 = (c0 * 16) * TK, aOff1 = ((c0 + 1) * 16) * TK;

    const int fr = lane & 15;
    const int fk = (lane >> 4) * 8;
    const int niter = klen / TK;

    // prologue: stage tile 0 into buffer 0
    gload_lds16(aS0, &As[0][aOff0]);
    gload_lds16(aS1, &As[0][aOff1]);
    gload_lds16(bS0, &Bs[0][aOff0]);
    gload_lds16(bS1, &Bs[0][aOff1]);

    int cur = 0;
    for (int it = 0; it < niter; ++it) {
        __syncthreads();      // buffer `cur` ready; prior reads of `cur^1` done
        if (it + 1 < niter) { // prefetch next tile into other buffer
            const int koff = (it + 1) * TK;
            gload_lds16(aS0 + koff, &As[cur ^ 1][aOff0]);
            gload_lds16(aS1 + koff, &As[cur ^ 1][aOff1]);
            gload_lds16(bS0 + koff, &Bs[cur ^ 1][aOff0]);
            gload_lds16(bS1 + koff, &Bs[cur ^ 1][aOff1]);
        }

        s16x8 af[4], bf[4];
#pragma unroll
        for (int i = 0; i < 4; i++)
            af[i] = *(const s16x8*)&As[cur][(wm + i * 16 + fr) * TK + fk];
#pragma unroll
        for (int j = 0; j < 4; j++)
            bf[j] = *(const s16x8*)&Bs[cur][(wn + j * 16 + fr) * TK + fk];
#pragma unroll
        for (int i = 0; i < 4; i++)
#pragma unroll
            for (int j = 0; j < 4; j++)
                acc[i][j] = __builtin_amdgcn_mfma_f32_16x16x32_bf16(
                    af[i], bf[j], acc[i][j], 0, 0, 0);
        cur ^= 1;
    }

    // epilogue: atomic accumulate (bias folded into chunk 0)
    const int ecol = lane & 15;
    const int erow = (lane >> 4) * 4;
#pragma unroll
    for (int j = 0; j < 4; j++) {
        const int gcol = n0 + wn + j * 16 + ecol;
        const float bv = (blockIdx.z == 0) ? bias[gcol] : 0.f;
#pragma unroll
        for (int i = 0; i < 4; i++) {
#pragma unroll
            for (int r = 0; r < 4; r++) {
                const int grow = m0 + wm + i * 16 + erow + r;
                atomicAdd(&C[(size_t)grow * N + gcol], acc[i][j][r] + bv);
            }
        }
    }
}

// ---------------------------------------------------------------------------
// Elementwise epilogues: fp32 -> bf16 (optional exact GELU), vectorized x4.
// ---------------------------------------------------------------------------
template<int GELU>
__global__ __launch_bounds__(256) void epi_bf16_kernel(
    const float* __restrict__ in, ushort* __restrict__ out, int n)
{
    const int i = (blockIdx.x * 256 + threadIdx.x) * 4;
    if (i >= n) return;
    float4 v = *(const float4*)(in + i);
    if (GELU) {
        v.x = v.x * 0.5f * (1.0f + erff(v.x * 0.70710678118654752f));
        v.y = v.y * 0.5f * (1.0f + erff(v.y * 0.70710678118654752f));
        v.z = v.z * 0.5f * (1.0f + erff(v.z * 0.70710678118654752f));
        v.w = v.w * 0.5f * (1.0f + erff(v.w * 0.70710678118654752f));
    }
    ushort4 o;
    o.x = f2bu(v.x); o.y = f2bu(v.y); o.z = f2bu(v.z); o.w = f2bu(v.w);
    *(ushort4*)(out + i) = o;
}

// ---------------------------------------------------------------------------
// MFMA flash attention (unchanged from round 4).
// ---------------------------------------------------------------------------
#define VST 68

__global__ __launch_bounds__(256) void flash_attn_mfma_kernel(
    const ushort* __restrict__ QKV, const int* __restrict__ amask,
    __hip_bfloat16* __restrict__ Octx)
{
    const int q0 = blockIdx.x * 64, h = blockIdx.y, b = blockIdx.z;
    const int tid = threadIdx.x, lane = tid & 63, wave = tid >> 6;
    __shared__ ushort Qs[64 * VST];       // [q][d]
    __shared__ ushort Ks[64 * VST];       // [key][d]
    __shared__ ushort Vt[64 * VST];       // [d][key]
    __shared__ ushort Ps[4][16 * VST];    // per-wave [q][key]
    __shared__ float biasS[S_];

    for (int i = tid; i < S_; i += 256)
        biasS[i] = amask[b * S_ + i] ? 0.f : -1e9f;

    {   // stage Q
        const ushort* qb = QKV + (size_t)(b * S_ + q0) * QKVN + h * DH_;
        const int q = tid >> 2, dg = (tid & 3) * 16;
        s16x8 v0 = *(const s16x8*)(qb + (size_t)q * QKVN + dg);
        s16x8 v1 = *(const s16x8*)(qb + (size_t)q * QKVN + dg + 8);
        ushort* d = &Qs[q * VST + dg];
        *(s16x4v*)(d)      = __builtin_shufflevector(v0, v0, 0, 1, 2, 3);
        *(s16x4v*)(d + 4)  = __builtin_shufflevector(v0, v0, 4, 5, 6, 7);
        *(s16x4v*)(d + 8)  = __builtin_shufflevector(v1, v1, 0, 1, 2, 3);
        *(s16x4v*)(d + 12) = __builtin_shufflevector(v1, v1, 4, 5, 6, 7);
    }
    __syncthreads();

    const int fm = lane & 15;
    const int fk = (lane >> 4) * 8;

    const s16x8 aq0 = lds_frag(&Qs[(wave * 16 + fm) * VST + fk]);
    const s16x8 aq1 = lds_frag(&Qs[(wave * 16 + fm) * VST + 32 + fk]);

    f32x4 acc[4];
#pragma unroll
    for (int j = 0; j < 4; j++) acc[j] = (f32x4){0.f, 0.f, 0.f, 0.f};
    float m_i[4], l_i[4];
#pragma unroll
    for (int r = 0; r < 4; r++) { m_i[r] = -INFINITY; l_i[r] = 0.f; }

    for (int kt = 0; kt < S_; kt += 64) {
        __syncthreads();
        {   // stage K tile [key][d]
            const ushort* kb = QKV + (size_t)(b * S_ + kt) * QKVN + H_ + h * DH_;
            const int ky = tid >> 2, dg = (tid & 3) * 16;
            s16x8 v0 = *(const s16x8*)(kb + (size_t)ky * QKVN + dg);
            s16x8 v1 = *(const s16x8*)(kb + (size_t)ky * QKVN + dg + 8);
            ushort* d = &Ks[ky * VST + dg];
            *(s16x4v*)(d)      = __builtin_shufflevector(v0, v0, 0, 1, 2, 3);
            *(s16x4v*)(d + 4)  = __builtin_shufflevector(v0, v0, 4, 5, 6, 7);
            *(s16x4v*)(d + 8)  = __builtin_shufflevector(v1, v1, 0, 1, 2, 3);
            *(s16x4v*)(d + 12) = __builtin_shufflevector(v1, v1, 4, 5, 6, 7);
        }
        {   // stage V transposed [d][key]
            const ushort* vb = QKV + (size_t)(b * S_ + kt) * QKVN + 2 * H_ + h * DH_;
            const int d = tid & 63, kg = tid >> 6;
#pragma unroll
            for (int kp = 0; kp < 8; kp++) {
                const int key = kg * 16 + kp * 2;
                ushort u0 = vb[(size_t)key * QKVN + d];
                ushort u1 = vb[(size_t)(key + 1) * QKVN + d];
                ushort2 u; u.x = u0; u.y = u1;
                *(ushort2*)&Vt[d * VST + key] = u;
            }
        }
        __syncthreads();

        f32x4 sc[4];
#pragma unroll
        for (int jj = 0; jj < 4; jj++) {
            s16x8 b0 = lds_frag(&Ks[(jj * 16 + fm) * VST + fk]);
            s16x8 b1 = lds_frag(&Ks[(jj * 16 + fm) * VST + 32 + fk]);
            f32x4 z = (f32x4){0.f, 0.f, 0.f, 0.f};
            z = __builtin_amdgcn_mfma_f32_16x16x32_bf16(aq0, b0, z, 0, 0, 0);
            z = __builtin_amdgcn_mfma_f32_16x16x32_bf16(aq1, b1, z, 0, 0, 0);
            sc[jj] = z;
        }

#pragma unroll
        for (int r = 0; r < 4; r++) {
            float mx = -INFINITY;
#pragma unroll
            for (int jj = 0; jj < 4; jj++) {
                float v = sc[jj][r] * 0.125f + biasS[kt + jj * 16 + fm];
                sc[jj][r] = v;
                mx = fmaxf(mx, v);
            }
#pragma unroll
            for (int msk = 1; msk < 16; msk <<= 1) mx = fmaxf(mx, __shfl_xor(mx, msk));
            const float newm = fmaxf(m_i[r], mx);
            const float alpha = __expf(m_i[r] - newm);
            m_i[r] = newm;
            float rs = 0.f;
#pragma unroll
            for (int jj = 0; jj < 4; jj++) {
                float p = __expf(sc[jj][r] - newm);
                sc[jj][r] = p; rs += p;
            }
#pragma unroll
            for (int msk = 1; msk < 16; msk <<= 1) rs += __shfl_xor(rs, msk);
            l_i[r] = l_i[r] * alpha + rs;
#pragma unroll
            for (int jj = 0; jj < 4; jj++) acc[jj][r] *= alpha;
        }

#pragma unroll
        for (int jj = 0; jj < 4; jj++)
#pragma unroll
            for (int r = 0; r < 4; r++)
                Ps[wave][((lane >> 4) * 4 + r) * VST + jj * 16 + fm] = f2bu(sc[jj][r]);

        const s16x8 ap0 = lds_frag(&Ps[wave][fm * VST + fk]);
        const s16x8 ap1 = lds_frag(&Ps[wave][fm * VST + 32 + fk]);

#pragma unroll
        for (int jj = 0; jj < 4; jj++) {
            s16x8 b0 = lds_frag(&Vt[(jj * 16 + fm) * VST + fk]);
            s16x8 b1 = lds_frag(&Vt[(jj * 16 + fm) * VST + 32 + fk]);
            acc[jj] = __builtin_amdgcn_mfma_f32_16x16x32_bf16(ap0, b0, acc[jj], 0, 0, 0);
            acc[jj] = __builtin_amdgcn_mfma_f32_16x16x32_bf16(ap1, b1, acc[jj], 0, 0, 0);
        }
    }

#pragma unroll
    for (int r = 0; r < 4; r++) {
        const int q = q0 + wave * 16 + (lane >> 4) * 4 + r;
        const float inv = 1.0f / l_i[r];
        __hip_bfloat16* op = Octx + (size_t)(b * S_ + q) * H_ + h * DH_;
#pragma unroll
        for (int jj = 0; jj < 4; jj++)
            op[jj * 16 + fm] = __float2bfloat16(acc[jj][r] * inv);
    }
}

// ---------------------------------------------------------------------------
// x = LN(x + delta) in place; also writes bf16 shadow xb.
// ---------------------------------------------------------------------------
__global__ __launch_bounds__(256) void add_ln_kernel(
    float* __restrict__ x, const float* __restrict__ delta,
    const float* __restrict__ g, const float* __restrict__ bb,
    __hip_bfloat16* __restrict__ xb)
{
    const int t = blockIdx.x;
    const int tid = threadIdx.x;
    __shared__ float red[256];
    const size_t base = (size_t)t * H_;

    float v[3];
    float sum = 0.f;
#pragma unroll
    for (int i = 0; i < 3; i++) {
        int c = tid + i * 256;
        v[i] = x[base + c] + delta[base + c];
        sum += v[i];
    }
    red[tid] = sum; __syncthreads();
    for (int st = 128; st > 0; st >>= 1) { if (tid < st) red[tid] += red[tid + st]; __syncthreads(); }
    const float mean = red[0] / (float)H_;
    __syncthreads();
    float s2 = 0.f;
#pragma unroll
    for (int i = 0; i < 3; i++) { float d = v[i] - mean; s2 += d * d; }
    red[tid] = s2; __syncthreads();
    for (int st = 128; st > 0; st >>= 1) { if (tid < st) red[tid] += red[tid + st]; __syncthreads(); }
    const float rstd = rsqrtf(red[0] / (float)H_ + 1e-12f);
#pragma unroll
    for (int i = 0; i < 3; i++) {
        int c = tid + i * 256;
        float o = (v[i] - mean) * rstd * g[c] + bb[c];
        x[base + c] = o;
        xb[base + c] = __float2bfloat16(o);
    }
}

// ---------------------------------------------------------------------------
// QA head
// ---------------------------------------------------------------------------
__global__ __launch_bounds__(256) void qa_kernel(
    const float* __restrict__ x, const float* __restrict__ qa_w,
    const float* __restrict__ qa_b, float* __restrict__ em)
{
    const int t = blockIdx.x;
    const int tid = threadIdx.x;
    __shared__ float r0[256], r1[256];
    float s0 = 0.f, s1 = 0.f;
#pragma unroll
    for (int i = 0; i < 3; i++) {
        int c = tid + i * 256;
        float xv = x[(size_t)t * H_ + c];
        s0 += xv * qa_w[c * 2 + 0];
        s1 += xv * qa_w[c * 2 + 1];
    }
    r0[tid] = s0; r1[tid] = s1; __syncthreads();
    for (int st = 128; st > 0; st >>= 1) {
        if (tid < st) { r0[tid] += r0[tid + st]; r1[tid] += r1[tid + st]; }
        __syncthreads();
    }
    if (tid == 0) {
        em[(size_t)t * 2 + 0] = r0[0] + qa_b[0];
        em[(size_t)t * 2 + 1] = r1[0] + qa_b[1];
    }
}

// ---------------------------------------------------------------------------
// CRF via log-semiring parallel reduction (unchanged from round 4).
// ---------------------------------------------------------------------------
__device__ __forceinline__ float lse2(float a, float b) {
    float m = fmaxf(a, b);
    return m + log1pf(expf(-fabsf(a - b)));
}

__device__ __forceinline__ float4 lsem_comb(float4 a, float4 b) {
    float4 r;
    r.x = lse2(a.x + b.x, a.y + b.z);
    r.y = lse2(a.x + b.y, a.y + b.w);
    r.z = lse2(a.z + b.x, a.w + b.z);
    r.w = lse2(a.z + b.y, a.w + b.w);
    return r;
}

__global__ __launch_bounds__(256) void crf_parallel_kernel(
    const float* __restrict__ em, const int* __restrict__ amask,
    const int* __restrict__ spos, const int* __restrict__ epos,
    const float* __restrict__ startT, const float* __restrict__ endT,
    const float* __restrict__ trans, float* __restrict__ out)
{
    __shared__ float4 mats[B_][64];
    __shared__ float numred[B_][64];
    __shared__ float cntred[B_][64];
    __shared__ float llh[B_];
    const int tid = threadIdx.x;
    const int s = tid >> 6;
    const int j = tid & 63;
    const float NEG = -1e30f;

    const int sp = spos[s], ep = epos[s];
    const bool valid = (sp >= 0) && (sp < S_) && (ep >= 0) && (ep < S_) && (sp <= ep);
    const float* e = em + (size_t)s * S_ * 2;
    const int* mk = amask + s * S_;
    const float t00 = trans[0], t01 = trans[1], t10 = trans[2], t11 = trans[3];

    float4 C = make_float4(0.f, NEG, NEG, 0.f);
    float num = 0.f, cnt = 0.f;
#pragma unroll
    for (int k = 0; k < 8; k++) {
        const int t = j * 8 + 1 + k;
        float4 Mt = make_float4(0.f, NEG, NEG, 0.f);
        if (t < S_ && mk[t]) {
            const float e0 = e[2 * t], e1 = e[2 * t + 1];
            Mt = make_float4(t00 + e0, t01 + e1, t10 + e0, t11 + e1);
            const int tp = (valid && (t - 1) >= sp && (t - 1) <= ep) ? 1 : 0;
            const int tc = (valid && t >= sp && t <= ep) ? 1 : 0;
            const float tr = tp ? (tc ? t11 : t10) : (tc ? t01 : t00);
            num += tr + (tc ? e1 : e0);
            cnt += 1.f;
        }
        C = (k == 0) ? Mt : lsem_comb(C, Mt);
    }
    if (j == 0) {
        const int tag0 = (valid && 0 >= sp && 0 <= ep) ? 1 : 0;
        num += startT[tag0] + e[tag0];
        cnt += mk[0] ? 1.f : 0.f;
    }
    mats[s][j] = C;
    numred[s][j] = num;
    cntred[s][j] = cnt;
    __syncthreads();

    for (int st = 32; st >= 1; st >>= 1) {
        float4 a, b;
        const bool act = (j < st);
        if (act) { a = mats[s][2 * j]; b = mats[s][2 * j + 1]; }
        __syncthreads();
        if (act) mats[s][j] = lsem_comb(a, b);
        __syncthreads();
    }
    for (int st = 32; st >= 1; st >>= 1) {
        if (j < st) {
            numred[s][j] += numred[s][j + st];
            cntred[s][j] += cntred[s][j + st];
        }
        __syncthreads();
    }

    if (j == 0) {
        float numT = numred[s][0];
        const int last_idx = (int)(cntred[s][0] + 0.5f) - 1;
        const int ltag = (valid && last_idx >= sp && last_idx <= ep) ? 1 : 0;
        numT += endT[ltag];
        const float a00 = startT[0] + e[0];
        const float a01 = startT[1] + e[1];
        const float4 P = mats[s][0];
        const float aF0 = lse2(a00 + P.x, a01 + P.z);
        const float aF1 = lse2(a00 + P.y, a01 + P.w);
        const float logZ = lse2(aF0 + endT[0], aF1 + endT[1]);
        llh[s] = numT - logZ;
    }
    __syncthreads();
    if (tid == 0)
        out[0] = -(llh[0] + llh[1] + llh[2] + llh[3]);
}

// ---------------------------------------------------------------------------
// Launch
// ---------------------------------------------------------------------------
extern "C" void kernel_launch(void* const* d_in, const int* in_sizes, int n_in,
                              void* d_out, int out_size, void* d_ws, size_t ws_size,
                              hipStream_t stream)
{
    const int*   input_ids  = (const int*)  d_in[0];
    const int*   attn_mask  = (const int*)  d_in[1];
    const int*   token_type = (const int*)  d_in[2];
    const int*   start_pos  = (const int*)  d_in[3];
    const int*   end_pos    = (const int*)  d_in[4];
    const float* word_emb   = (const float*)d_in[5];
    const float* pos_emb    = (const float*)d_in[6];
    const float* type_emb   = (const float*)d_in[7];
    const float* emb_ln_g   = (const float*)d_in[8];
    const float* emb_ln_b   = (const float*)d_in[9];
    const float* Wq         = (const float*)d_in[10];
    const float* bq         = (const float*)d_in[11];
    const float* Wk         = (const float*)d_in[12];
    const float* bk         = (const float*)d_in[13];
    const float* Wv         = (const float*)d_in[14];
    const float* bv         = (const float*)d_in[15];
    const float* Wo         = (const float*)d_in[16];
    const float* bo         = (const float*)d_in[17];
    const float* ln1_g      = (const float*)d_in[18];
    const float* ln1_b      = (const float*)d_in[19];
    const float* W1         = (const float*)d_in[20];
    const float* b1         = (const float*)d_in[21];
    const float* W2         = (const float*)d_in[22];
    const float* b2         = (const float*)d_in[23];
    const float* ln2_g      = (const float*)d_in[24];
    const float* ln2_b      = (const float*)d_in[25];
    const float* qa_w       = (const float*)d_in[26];
    const float* qa_b       = (const float*)d_in[27];
    const float* crf_start  = (const float*)d_in[28];
    const float* crf_end    = (const float*)d_in[29];
    const float* crf_trans  = (const float*)d_in[30];
    float* out = (float*)d_out;

    // Workspace carve-up (~80 MB)
    float*  x      = (float*)d_ws;                                  // M*H
    float*  slab   = x + (size_t)M_ * H_;                           // M*3072 (qkv_f32 / h_f32)
    float*  tmp768 = slab + (size_t)M_ * FF_;                       // M*H   (contiguous after slab)
    float*  emis   = tmp768 + (size_t)M_ * H_;                      // M*2
    float*  b_qkv  = emis + (size_t)M_ * 2;                         // 2304
    ushort* xb     = (ushort*)(b_qkv + QKVN);                       // M*H
    ushort* qkvb   = xb + (size_t)M_ * H_;                          // M*2304
    ushort* ctxb   = qkvb + (size_t)M_ * QKVN;                      // M*H
    ushort* hb     = ctxb + (size_t)M_ * H_;                        // M*FF
    ushort* Wt_qkv = hb + (size_t)M_ * FF_;                         // 2304*768
    ushort* Wt_o   = Wt_qkv + (size_t)QKVN * H_;                    // 768*768
    ushort* Wt_1   = Wt_o + (size_t)H_ * H_;                        // 3072*768
    ushort* Wt_2   = Wt_1 + (size_t)FF_ * H_;                       // 768*3072

    const size_t zbytes = (size_t)M_ * (FF_ + H_) * sizeof(float);  // slab + tmp768

    dim3 blk(256);
    dim3 tblk(32, 8);

    embed_ln_kernel<<<M_, blk, 0, stream>>>(input_ids, token_type, word_emb, pos_emb,
                                            type_emb, emb_ln_g, emb_ln_b, x,
                                            (__hip_bfloat16*)xb);

    // split-K grids: >= 2 blocks/CU everywhere
    const dim3 gQKV(QKVN / TN, M_ / TM, 2);   // 18 x 16 x 2 = 576
    const dim3 gO(H_ / TN, M_ / TM, 4);       //  6 x 16 x 4 = 384
    const dim3 gF1(FF_ / TN, M_ / TM, 2);     // 24 x 16 x 2 = 768
    const dim3 gF2(H_ / TN, M_ / TM, 8);      //  6 x 16 x 8 = 768
    const dim3 gA(S_ / 64, NH_, B_);          //  8 x 12 x 4 = 384

    for (int l = 0; l < L_; l++) {
        prep_layer_kernel<<<6921, tblk, 0, stream>>>(
            Wq + (size_t)l * H_ * H_, Wk + (size_t)l * H_ * H_,
            Wv + (size_t)l * H_ * H_, Wo + (size_t)l * H_ * H_,
            W1 + (size_t)l * H_ * FF_, W2 + (size_t)l * FF_ * H_,
            bq + l * H_, bk + l * H_, bv + l * H_,
            Wt_qkv, Wt_o, Wt_1, Wt_2, b_qkv);

        // ---- attention half ----
        hipMemsetAsync(slab, 0, zbytes, stream);                 // qkv acc + tmp768
        gemm_splitk_kernel<<<gQKV, blk, 0, stream>>>(
            xb, Wt_qkv, b_qkv, slab, H_, QKVN, H_ / 2);
        epi_bf16_kernel<0><<<(M_ * QKVN) / 1024, blk, 0, stream>>>(
            slab, qkvb, M_ * QKVN);

        flash_attn_mfma_kernel<<<gA, blk, 0, stream>>>(
            qkvb, attn_mask, (__hip_bfloat16*)ctxb);

        gemm_splitk_kernel<<<gO, blk, 0, stream>>>(
            ctxb, Wt_o, bo + l * H_, tmp768, H_, H_, H_ / 4);
        add_ln_kernel<<<M_, blk, 0, stream>>>(x, tmp768, ln1_g + l * H_, ln1_b + l * H_,
                                              (__hip_bfloat16*)xb);

        // ---- FFN half ----
        hipMemsetAsync(slab, 0, zbytes, stream);                 // h acc + tmp768
        gemm_splitk_kernel<<<gF1, blk, 0, stream>>>(
            xb, Wt_1, b1 + l * FF_, slab, H_, FF_, H_ / 2);
        epi_bf16_kernel<1><<<(M_ * FF_) / 1024, blk, 0, stream>>>(
            slab, hb, M_ * FF_);

        gemm_splitk_kernel<<<gF2, blk, 0, stream>>>(
            hb, Wt_2, b2 + l * H_, tmp768, FF_, H_, FF_ / 8);
        add_ln_kernel<<<M_, blk, 0, stream>>>(x, tmp768, ln2_g + l * H_, ln2_b + l * H_,
                                              (__hip_bfloat16*)xb);
    }

    qa_kernel<<<M_, blk, 0, stream>>>(x, qa_w, qa_b, emis);
    crf_parallel_kernel<<<1, 256, 0, stream>>>(emis, attn_mask, start_pos, end_pos,
                                               crf_start, crf_end, crf_trans, out);
}

// Round 6
// 1206.867 us; speedup vs baseline: 1.4330x; 1.4330x over previous
//
#include <hip/hip_runtime.h>
#include <hip/hip_bf16.h>
#include <math.h>

// Problem constants
#define B_  4
#define S_  512
#define H_  768
#define NH_ 12
#define DH_ 64
#define FF_ 3072
#define L_  6
#define V_  30522
#define QKVN 2304          // fused QKV output width
#define M_  (B_ * S_)      // 2048 tokens

typedef short s16x8 __attribute__((ext_vector_type(8)));
typedef short s16x4v __attribute__((ext_vector_type(4)));
typedef float f32x4 __attribute__((ext_vector_type(4)));

__device__ __forceinline__ void gload_lds16(const void* g, void* l) {
    __builtin_amdgcn_global_load_lds(
        (const __attribute__((address_space(1))) void*)g,
        (__attribute__((address_space(3))) void*)l,
        16, 0, 0);
}

__device__ __forceinline__ ushort f2bu(float x) {
    __hip_bfloat16 h = __float2bfloat16(x);
    return *(ushort*)&h;
}

// read 8 contiguous bf16 from LDS as two 8B chunks (8B-aligned offsets only)
__device__ __forceinline__ s16x8 lds_frag(const ushort* p) {
    s16x4v lo = *(const s16x4v*)p;
    s16x4v hi = *(const s16x4v*)(p + 4);
    return __builtin_shufflevector(lo, hi, 0, 1, 2, 3, 4, 5, 6, 7);
}

// ---------------------------------------------------------------------------
// Embedding gather + LayerNorm -> x (fp32) and xb (bf16 shadow).
// ---------------------------------------------------------------------------
__global__ __launch_bounds__(256) void embed_ln_kernel(
    const int* __restrict__ ids, const int* __restrict__ tt,
    const float* __restrict__ wemb, const float* __restrict__ pemb,
    const float* __restrict__ temb, const float* __restrict__ g,
    const float* __restrict__ bb, float* __restrict__ x,
    __hip_bfloat16* __restrict__ xb)
{
    const int t = blockIdx.x;
    const int s = t % S_;
    const int tid = threadIdx.x;
    __shared__ float red[256];

    const float* wr = wemb + (size_t)ids[t] * H_;
    const float* pr = pemb + (size_t)s * H_;
    const float* tr = temb + (size_t)tt[t] * H_;

    float v[3];
    float sum = 0.f;
#pragma unroll
    for (int i = 0; i < 3; i++) {
        int c = tid + i * 256;
        v[i] = wr[c] + pr[c] + tr[c];
        sum += v[i];
    }
    red[tid] = sum; __syncthreads();
    for (int st = 128; st > 0; st >>= 1) { if (tid < st) red[tid] += red[tid + st]; __syncthreads(); }
    const float mean = red[0] / (float)H_;
    __syncthreads();
    float s2 = 0.f;
#pragma unroll
    for (int i = 0; i < 3; i++) { float d = v[i] - mean; s2 += d * d; }
    red[tid] = s2; __syncthreads();
    for (int st = 128; st > 0; st >>= 1) { if (tid < st) red[tid] += red[tid + st]; __syncthreads(); }
    const float rstd = rsqrtf(red[0] / (float)H_ + 1e-12f);
#pragma unroll
    for (int i = 0; i < 3; i++) {
        int c = tid + i * 256;
        float o = (v[i] - mean) * rstd * g[c] + bb[c];
        x[(size_t)t * H_ + c] = o;
        xb[(size_t)t * H_ + c] = __float2bfloat16(o);
    }
}

// ---------------------------------------------------------------------------
// Per-layer weight prep, ONE launch: transposes wq|wk|wv -> Wt_qkv, wo -> Wt_o,
// w1 -> Wt_1, w2 -> Wt_2 (all fp32 [K][N] -> bf16 [N][K]) + bias concat.
// ---------------------------------------------------------------------------
__device__ __forceinline__ void tr_tile(
    const float* __restrict__ src, ushort* __restrict__ dst,
    int K, int N, int t, int ncols, float (*tile)[33])
{
    const int tx = threadIdx.x, ty = threadIdx.y;
    const int n0 = (t % ncols) * 32;
    const int k0 = (t / ncols) * 32;
#pragma unroll
    for (int i = 0; i < 4; i++)
        tile[ty + 8 * i][tx] = src[(size_t)(k0 + ty + 8 * i) * N + n0 + tx];
    __syncthreads();
#pragma unroll
    for (int i = 0; i < 4; i++)
        dst[(size_t)(n0 + ty + 8 * i) * K + k0 + tx] = f2bu(tile[tx][ty + 8 * i]);
}

__global__ __launch_bounds__(256) void prep_layer_kernel(
    const float* __restrict__ wq, const float* __restrict__ wk,
    const float* __restrict__ wv, const float* __restrict__ wo,
    const float* __restrict__ w1, const float* __restrict__ w2,
    const float* __restrict__ bq, const float* __restrict__ bk,
    const float* __restrict__ bv,
    ushort* __restrict__ Wt_qkv, ushort* __restrict__ Wt_o,
    ushort* __restrict__ Wt_1, ushort* __restrict__ Wt_2,
    float* __restrict__ b_qkv)
{
    __shared__ float tile[32][33];
    const int id = blockIdx.x;
    if (id < 1728) {                      // QKV: 3 x 576 tiles of 768x768
        const int mat = id / 576, t = id % 576;
        const float* src = (mat == 0) ? wq : (mat == 1) ? wk : wv;
        tr_tile(src, Wt_qkv + (size_t)mat * H_ * H_, H_, H_, t, 24, tile);
    } else if (id < 2304) {               // O: 576 tiles
        tr_tile(wo, Wt_o, H_, H_, id - 1728, 24, tile);
    } else if (id < 4608) {               // W1: 768x3072, 2304 tiles
        tr_tile(w1, Wt_1, H_, FF_, id - 2304, 96, tile);
    } else if (id < 6912) {               // W2: 3072x768, 2304 tiles
        tr_tile(w2, Wt_2, FF_, H_, id - 4608, 24, tile);
    } else {                              // bias concat (9 blocks x 256)
        int i = (id - 6912) * 256 + threadIdx.y * 32 + threadIdx.x;
        if (i < QKVN)
            b_qkv[i] = (i < H_) ? bq[i] : ((i < 2 * H_) ? bk[i - H_] : bv[i - 2 * H_]);
    }
}

// ---------------------------------------------------------------------------
// bf16 MFMA GEMM: C[M][N] = A[M][K] @ Bt[N][K]^T + bias.
// 128x128 tile, BK=64, double-buffered LDS (64KB), XOR-swizzled k-slots.
// 256 thr = 4 waves (2x2 of 64x64), 16x16x32 MFMA, 32 MFMA/wave/iter.
// LDS row = 64 ushorts (128B); slot s of row r holds k-group s^(r&7) --
// the swizzle is applied on the per-lane global SOURCE address so the
// global_load_lds destination stays contiguous (wave-uniform base+lane*16).
// EPI: 0=none 1=exact gelu.  OUTBF: bf16 out.
// ---------------------------------------------------------------------------
#define TM 128
#define TN 128
#define TK 64

template<int EPI, int OUTBF>
__global__ __launch_bounds__(256) void gemm_mfma_kernel(
    const ushort* __restrict__ A, const ushort* __restrict__ Bt,
    const float* __restrict__ bias, void* __restrict__ Cout,
    int M, int K, int N)
{
    __shared__ ushort As[2][TM * TK];
    __shared__ ushort Bs[2][TN * TK];
    const int tid  = threadIdx.x;
    const int lane = tid & 63;
    const int wave = tid >> 6;
    const int m0 = blockIdx.y * TM;
    const int n0 = blockIdx.x * TN;
    const int wm = (wave >> 1) * 64;
    const int wn = (wave & 1) * 64;

    f32x4 acc[4][4];
#pragma unroll
    for (int i = 0; i < 4; i++)
#pragma unroll
        for (int j = 0; j < 4; j++)
            acc[i][j] = (f32x4){0.f, 0.f, 0.f, 0.f};

    // ---- staging setup: wave stages rows [wave*32, wave*32+32) of A and B,
    // as 4 chunks of 8 rows (1KB each).  lane -> row r8=lane>>3, slot s=lane&7.
    // slot s of row r holds k-group g = s ^ (r&7); chunk bases are multiples
    // of 8 so r&7 == r8.
    const int r8 = lane >> 3;
    const int sl = lane & 7;
    const int gk = (sl ^ r8) * 8;          // element offset of this lane's k-group
    const ushort* aSrc[4];
    const ushort* bSrc[4];
    int dOff[4];
#pragma unroll
    for (int c = 0; c < 4; c++) {
        const int R = wave * 32 + c * 8;
        aSrc[c] = A  + (size_t)(m0 + R + r8) * K + gk;
        bSrc[c] = Bt + (size_t)(n0 + R + r8) * K + gk;
        dOff[c] = R * TK;                  // contiguous 1KB chunk base
    }

    const int fr = lane & 15;              // fragment row (m or n)
    const int q4 = lane >> 4;              // k-group within 32-k subtile
    // fragment LDS offsets (k-invariant): row*64 + ((ksub*4+q4)^(row&7))*8
    int offA[4][2], offB[4][2];
#pragma unroll
    for (int i = 0; i < 4; i++) {
        const int rowA = wm + i * 16 + fr;
        const int rowB = wn + i * 16 + fr;
#pragma unroll
        for (int ks = 0; ks < 2; ks++) {
            offA[i][ks] = rowA * TK + (((ks * 4 + q4) ^ (rowA & 7)) * 8);
            offB[i][ks] = rowB * TK + (((ks * 4 + q4) ^ (rowB & 7)) * 8);
        }
    }

    const int niter = K / TK;

    // prologue: stage tile 0 into buffer 0
#pragma unroll
    for (int c = 0; c < 4; c++) {
        gload_lds16(aSrc[c], &As[0][dOff[c]]);
        gload_lds16(bSrc[c], &Bs[0][dOff[c]]);
    }

    int cur = 0;
    for (int it = 0; it < niter; ++it) {
        __syncthreads();      // drains the in-flight prefetch for buffer `cur`
        if (it + 1 < niter) { // prefetch next tile; stays in flight during compute
            const int koff = (it + 1) * TK;
#pragma unroll
            for (int c = 0; c < 4; c++) {
                gload_lds16(aSrc[c] + koff, &As[cur ^ 1][dOff[c]]);
                gload_lds16(bSrc[c] + koff, &Bs[cur ^ 1][dOff[c]]);
            }
        }

#pragma unroll
        for (int ks = 0; ks < 2; ks++) {
            s16x8 af[4], bf[4];
#pragma unroll
            for (int i = 0; i < 4; i++) af[i] = lds_frag(&As[cur][offA[i][ks]]);
#pragma unroll
            for (int j = 0; j < 4; j++) bf[j] = lds_frag(&Bs[cur][offB[j][ks]]);
#pragma unroll
            for (int i = 0; i < 4; i++)
#pragma unroll
                for (int j = 0; j < 4; j++)
                    acc[i][j] = __builtin_amdgcn_mfma_f32_16x16x32_bf16(
                        af[i], bf[j], acc[i][j], 0, 0, 0);
        }
        cur ^= 1;
    }

    // epilogue: C/D layout col=lane&15, row=(lane>>4)*4+reg
    const int ecol = lane & 15;
    const int erow = (lane >> 4) * 4;
#pragma unroll
    for (int j = 0; j < 4; j++) {
        const int gcol = n0 + wn + j * 16 + ecol;
        const float bv = bias[gcol];
#pragma unroll
        for (int i = 0; i < 4; i++) {
#pragma unroll
            for (int r = 0; r < 4; r++) {
                const int grow = m0 + wm + i * 16 + erow + r;
                float v = acc[i][j][r] + bv;
                if (EPI == 1) v = v * 0.5f * (1.0f + erff(v * 0.70710678118654752f));
                if (OUTBF)
                    ((ushort*)Cout)[(size_t)grow * N + gcol] = f2bu(v);
                else
                    ((float*)Cout)[(size_t)grow * N + gcol] = v;
            }
        }
    }
}

// ---------------------------------------------------------------------------
// MFMA flash attention (unchanged).
// ---------------------------------------------------------------------------
#define VST 68

__global__ __launch_bounds__(256) void flash_attn_mfma_kernel(
    const ushort* __restrict__ QKV, const int* __restrict__ amask,
    __hip_bfloat16* __restrict__ Octx)
{
    const int q0 = blockIdx.x * 64, h = blockIdx.y, b = blockIdx.z;
    const int tid = threadIdx.x, lane = tid & 63, wave = tid >> 6;
    __shared__ ushort Qs[64 * VST];       // [q][d]
    __shared__ ushort Ks[64 * VST];       // [key][d]
    __shared__ ushort Vt[64 * VST];       // [d][key]
    __shared__ ushort Ps[4][16 * VST];    // per-wave [q][key]
    __shared__ float biasS[S_];

    for (int i = tid; i < S_; i += 256)
        biasS[i] = amask[b * S_ + i] ? 0.f : -1e9f;

    {   // stage Q
        const ushort* qb = QKV + (size_t)(b * S_ + q0) * QKVN + h * DH_;
        const int q = tid >> 2, dg = (tid & 3) * 16;
        s16x8 v0 = *(const s16x8*)(qb + (size_t)q * QKVN + dg);
        s16x8 v1 = *(const s16x8*)(qb + (size_t)q * QKVN + dg + 8);
        ushort* d = &Qs[q * VST + dg];
        *(s16x4v*)(d)      = __builtin_shufflevector(v0, v0, 0, 1, 2, 3);
        *(s16x4v*)(d + 4)  = __builtin_shufflevector(v0, v0, 4, 5, 6, 7);
        *(s16x4v*)(d + 8)  = __builtin_shufflevector(v1, v1, 0, 1, 2, 3);
        *(s16x4v*)(d + 12) = __builtin_shufflevector(v1, v1, 4, 5, 6, 7);
    }
    __syncthreads();

    const int fm = lane & 15;
    const int fk = (lane >> 4) * 8;

    const s16x8 aq0 = lds_frag(&Qs[(wave * 16 + fm) * VST + fk]);
    const s16x8 aq1 = lds_frag(&Qs[(wave * 16 + fm) * VST + 32 + fk]);

    f32x4 acc[4];
#pragma unroll
    for (int j = 0; j < 4; j++) acc[j] = (f32x4){0.f, 0.f, 0.f, 0.f};
    float m_i[4], l_i[4];
#pragma unroll
    for (int r = 0; r < 4; r++) { m_i[r] = -INFINITY; l_i[r] = 0.f; }

    for (int kt = 0; kt < S_; kt += 64) {
        __syncthreads();
        {   // stage K tile [key][d]
            const ushort* kb = QKV + (size_t)(b * S_ + kt) * QKVN + H_ + h * DH_;
            const int ky = tid >> 2, dg = (tid & 3) * 16;
            s16x8 v0 = *(const s16x8*)(kb + (size_t)ky * QKVN + dg);
            s16x8 v1 = *(const s16x8*)(kb + (size_t)ky * QKVN + dg + 8);
            ushort* d = &Ks[ky * VST + dg];
            *(s16x4v*)(d)      = __builtin_shufflevector(v0, v0, 0, 1, 2, 3);
            *(s16x4v*)(d + 4)  = __builtin_shufflevector(v0, v0, 4, 5, 6, 7);
            *(s16x4v*)(d + 8)  = __builtin_shufflevector(v1, v1, 0, 1, 2, 3);
            *(s16x4v*)(d + 12) = __builtin_shufflevector(v1, v1, 4, 5, 6, 7);
        }
        {   // stage V transposed [d][key]
            const ushort* vb = QKV + (size_t)(b * S_ + kt) * QKVN + 2 * H_ + h * DH_;
            const int d = tid & 63, kg = tid >> 6;
#pragma unroll
            for (int kp = 0; kp < 8; kp++) {
                const int key = kg * 16 + kp * 2;
                ushort u0 = vb[(size_t)key * QKVN + d];
                ushort u1 = vb[(size_t)(key + 1) * QKVN + d];
                ushort2 u; u.x = u0; u.y = u1;
                *(ushort2*)&Vt[d * VST + key] = u;
            }
        }
        __syncthreads();

        f32x4 sc[4];
#pragma unroll
        for (int jj = 0; jj < 4; jj++) {
            s16x8 b0 = lds_frag(&Ks[(jj * 16 + fm) * VST + fk]);
            s16x8 b1 = lds_frag(&Ks[(jj * 16 + fm) * VST + 32 + fk]);
            f32x4 z = (f32x4){0.f, 0.f, 0.f, 0.f};
            z = __builtin_amdgcn_mfma_f32_16x16x32_bf16(aq0, b0, z, 0, 0, 0);
            z = __builtin_amdgcn_mfma_f32_16x16x32_bf16(aq1, b1, z, 0, 0, 0);
            sc[jj] = z;
        }

#pragma unroll
        for (int r = 0; r < 4; r++) {
            float mx = -INFINITY;
#pragma unroll
            for (int jj = 0; jj < 4; jj++) {
                float v = sc[jj][r] * 0.125f + biasS[kt + jj * 16 + fm];
                sc[jj][r] = v;
                mx = fmaxf(mx, v);
            }
#pragma unroll
            for (int msk = 1; msk < 16; msk <<= 1) mx = fmaxf(mx, __shfl_xor(mx, msk));
            const float newm = fmaxf(m_i[r], mx);
            const float alpha = __expf(m_i[r] - newm);
            m_i[r] = newm;
            float rs = 0.f;
#pragma unroll
            for (int jj = 0; jj < 4; jj++) {
                float p = __expf(sc[jj][r] - newm);
                sc[jj][r] = p; rs += p;
            }
#pragma unroll
            for (int msk = 1; msk < 16; msk <<= 1) rs += __shfl_xor(rs, msk);
            l_i[r] = l_i[r] * alpha + rs;
#pragma unroll
            for (int jj = 0; jj < 4; jj++) acc[jj][r] *= alpha;
        }

#pragma unroll
        for (int jj = 0; jj < 4; jj++)
#pragma unroll
            for (int r = 0; r < 4; r++)
                Ps[wave][((lane >> 4) * 4 + r) * VST + jj * 16 + fm] = f2bu(sc[jj][r]);

        const s16x8 ap0 = lds_frag(&Ps[wave][fm * VST + fk]);
        const s16x8 ap1 = lds_frag(&Ps[wave][fm * VST + 32 + fk]);

#pragma unroll
        for (int jj = 0; jj < 4; jj++) {
            s16x8 b0 = lds_frag(&Vt[(jj * 16 + fm) * VST + fk]);
            s16x8 b1 = lds_frag(&Vt[(jj * 16 + fm) * VST + 32 + fk]);
            acc[jj] = __builtin_amdgcn_mfma_f32_16x16x32_bf16(ap0, b0, acc[jj], 0, 0, 0);
            acc[jj] = __builtin_amdgcn_mfma_f32_16x16x32_bf16(ap1, b1, acc[jj], 0, 0, 0);
        }
    }

#pragma unroll
    for (int r = 0; r < 4; r++) {
        const int q = q0 + wave * 16 + (lane >> 4) * 4 + r;
        const float inv = 1.0f / l_i[r];
        __hip_bfloat16* op = Octx + (size_t)(b * S_ + q) * H_ + h * DH_;
#pragma unroll
        for (int jj = 0; jj < 4; jj++)
            op[jj * 16 + fm] = __float2bfloat16(acc[jj][r] * inv);
    }
}

// ---------------------------------------------------------------------------
// x = LN(x + delta) in place; also writes bf16 shadow xb.
// ---------------------------------------------------------------------------
__global__ __launch_bounds__(256) void add_ln_kernel(
    float* __restrict__ x, const float* __restrict__ delta,
    const float* __restrict__ g, const float* __restrict__ bb,
    __hip_bfloat16* __restrict__ xb)
{
    const int t = blockIdx.x;
    const int tid = threadIdx.x;
    __shared__ float red[256];
    const size_t base = (size_t)t * H_;

    float v[3];
    float sum = 0.f;
#pragma unroll
    for (int i = 0; i < 3; i++) {
        int c = tid + i * 256;
        v[i] = x[base + c] + delta[base + c];
        sum += v[i];
    }
    red[tid] = sum; __syncthreads();
    for (int st = 128; st > 0; st >>= 1) { if (tid < st) red[tid] += red[tid + st]; __syncthreads(); }
    const float mean = red[0] / (float)H_;
    __syncthreads();
    float s2 = 0.f;
#pragma unroll
    for (int i = 0; i < 3; i++) { float d = v[i] - mean; s2 += d * d; }
    red[tid] = s2; __syncthreads();
    for (int st = 128; st > 0; st >>= 1) { if (tid < st) red[tid] += red[tid + st]; __syncthreads(); }
    const float rstd = rsqrtf(red[0] / (float)H_ + 1e-12f);
#pragma unroll
    for (int i = 0; i < 3; i++) {
        int c = tid + i * 256;
        float o = (v[i] - mean) * rstd * g[c] + bb[c];
        x[base + c] = o;
        xb[base + c] = __float2bfloat16(o);
    }
}

// ---------------------------------------------------------------------------
// QA head
// ---------------------------------------------------------------------------
__global__ __launch_bounds__(256) void qa_kernel(
    const float* __restrict__ x, const float* __restrict__ qa_w,
    const float* __restrict__ qa_b, float* __restrict__ em)
{
    const int t = blockIdx.x;
    const int tid = threadIdx.x;
    __shared__ float r0[256], r1[256];
    float s0 = 0.f, s1 = 0.f;
#pragma unroll
    for (int i = 0; i < 3; i++) {
        int c = tid + i * 256;
        float xv = x[(size_t)t * H_ + c];
        s0 += xv * qa_w[c * 2 + 0];
        s1 += xv * qa_w[c * 2 + 1];
    }
    r0[tid] = s0; r1[tid] = s1; __syncthreads();
    for (int st = 128; st > 0; st >>= 1) {
        if (tid < st) { r0[tid] += r0[tid + st]; r1[tid] += r1[tid + st]; }
        __syncthreads();
    }
    if (tid == 0) {
        em[(size_t)t * 2 + 0] = r0[0] + qa_b[0];
        em[(size_t)t * 2 + 1] = r1[0] + qa_b[1];
    }
}

// ---------------------------------------------------------------------------
// CRF via log-semiring parallel reduction (unchanged).
// ---------------------------------------------------------------------------
__device__ __forceinline__ float lse2(float a, float b) {
    float m = fmaxf(a, b);
    return m + log1pf(expf(-fabsf(a - b)));
}

__device__ __forceinline__ float4 lsem_comb(float4 a, float4 b) {
    float4 r;
    r.x = lse2(a.x + b.x, a.y + b.z);
    r.y = lse2(a.x + b.y, a.y + b.w);
    r.z = lse2(a.z + b.x, a.w + b.z);
    r.w = lse2(a.z + b.y, a.w + b.w);
    return r;
}

__global__ __launch_bounds__(256) void crf_parallel_kernel(
    const float* __restrict__ em, const int* __restrict__ amask,
    const int* __restrict__ spos, const int* __restrict__ epos,
    const float* __restrict__ startT, const float* __restrict__ endT,
    const float* __restrict__ trans, float* __restrict__ out)
{
    __shared__ float4 mats[B_][64];
    __shared__ float numred[B_][64];
    __shared__ float cntred[B_][64];
    __shared__ float llh[B_];
    const int tid = threadIdx.x;
    const int s = tid >> 6;
    const int j = tid & 63;
    const float NEG = -1e30f;

    const int sp = spos[s], ep = epos[s];
    const bool valid = (sp >= 0) && (sp < S_) && (ep >= 0) && (ep < S_) && (sp <= ep);
    const float* e = em + (size_t)s * S_ * 2;
    const int* mk = amask + s * S_;
    const float t00 = trans[0], t01 = trans[1], t10 = trans[2], t11 = trans[3];

    float4 C = make_float4(0.f, NEG, NEG, 0.f);
    float num = 0.f, cnt = 0.f;
#pragma unroll
    for (int k = 0; k < 8; k++) {
        const int t = j * 8 + 1 + k;
        float4 Mt = make_float4(0.f, NEG, NEG, 0.f);
        if (t < S_ && mk[t]) {
            const float e0 = e[2 * t], e1 = e[2 * t + 1];
            Mt = make_float4(t00 + e0, t01 + e1, t10 + e0, t11 + e1);
            const int tp = (valid && (t - 1) >= sp && (t - 1) <= ep) ? 1 : 0;
            const int tc = (valid && t >= sp && t <= ep) ? 1 : 0;
            const float tr = tp ? (tc ? t11 : t10) : (tc ? t01 : t00);
            num += tr + (tc ? e1 : e0);
            cnt += 1.f;
        }
        C = (k == 0) ? Mt : lsem_comb(C, Mt);
    }
    if (j == 0) {
        const int tag0 = (valid && 0 >= sp && 0 <= ep) ? 1 : 0;
        num += startT[tag0] + e[tag0];
        cnt += mk[0] ? 1.f : 0.f;
    }
    mats[s][j] = C;
    numred[s][j] = num;
    cntred[s][j] = cnt;
    __syncthreads();

    for (int st = 32; st >= 1; st >>= 1) {
        float4 a, b;
        const bool act = (j < st);
        if (act) { a = mats[s][2 * j]; b = mats[s][2 * j + 1]; }
        __syncthreads();
        if (act) mats[s][j] = lsem_comb(a, b);
        __syncthreads();
    }
    for (int st = 32; st >= 1; st >>= 1) {
        if (j < st) {
            numred[s][j] += numred[s][j + st];
            cntred[s][j] += cntred[s][j + st];
        }
        __syncthreads();
    }

    if (j == 0) {
        float numT = numred[s][0];
        const int last_idx = (int)(cntred[s][0] + 0.5f) - 1;
        const int ltag = (valid && last_idx >= sp && last_idx <= ep) ? 1 : 0;
        numT += endT[ltag];
        const float a00 = startT[0] + e[0];
        const float a01 = startT[1] + e[1];
        const float4 P = mats[s][0];
        const float aF0 = lse2(a00 + P.x, a01 + P.z);
        const float aF1 = lse2(a00 + P.y, a01 + P.w);
        const float logZ = lse2(aF0 + endT[0], aF1 + endT[1]);
        llh[s] = numT - logZ;
    }
    __syncthreads();
    if (tid == 0)
        out[0] = -(llh[0] + llh[1] + llh[2] + llh[3]);
}

// ---------------------------------------------------------------------------
// Launch
// ---------------------------------------------------------------------------
extern "C" void kernel_launch(void* const* d_in, const int* in_sizes, int n_in,
                              void* d_out, int out_size, void* d_ws, size_t ws_size,
                              hipStream_t stream)
{
    const int*   input_ids  = (const int*)  d_in[0];
    const int*   attn_mask  = (const int*)  d_in[1];
    const int*   token_type = (const int*)  d_in[2];
    const int*   start_pos  = (const int*)  d_in[3];
    const int*   end_pos    = (const int*)  d_in[4];
    const float* word_emb   = (const float*)d_in[5];
    const float* pos_emb    = (const float*)d_in[6];
    const float* type_emb   = (const float*)d_in[7];
    const float* emb_ln_g   = (const float*)d_in[8];
    const float* emb_ln_b   = (const float*)d_in[9];
    const float* Wq         = (const float*)d_in[10];
    const float* bq         = (const float*)d_in[11];
    const float* Wk         = (const float*)d_in[12];
    const float* bk         = (const float*)d_in[13];
    const float* Wv         = (const float*)d_in[14];
    const float* bv         = (const float*)d_in[15];
    const float* Wo         = (const float*)d_in[16];
    const float* bo         = (const float*)d_in[17];
    const float* ln1_g      = (const float*)d_in[18];
    const float* ln1_b      = (const float*)d_in[19];
    const float* W1         = (const float*)d_in[20];
    const float* b1         = (const float*)d_in[21];
    const float* W2         = (const float*)d_in[22];
    const float* b2         = (const float*)d_in[23];
    const float* ln2_g      = (const float*)d_in[24];
    const float* ln2_b      = (const float*)d_in[25];
    const float* qa_w       = (const float*)d_in[26];
    const float* qa_b       = (const float*)d_in[27];
    const float* crf_start  = (const float*)d_in[28];
    const float* crf_end    = (const float*)d_in[29];
    const float* crf_trans  = (const float*)d_in[30];
    float* out = (float*)d_out;

    // Workspace carve-up
    float*  x      = (float*)d_ws;                                  // M*H
    float*  tmp768 = x + (size_t)M_ * H_;                           // M*H
    float*  emis   = tmp768 + (size_t)M_ * H_;                      // M*2
    float*  b_qkv  = emis + (size_t)M_ * 2;                         // 2304
    ushort* xb     = (ushort*)(b_qkv + QKVN);                       // M*H
    ushort* qkvb   = xb + (size_t)M_ * H_;                          // M*2304
    ushort* ctxb   = qkvb + (size_t)M_ * QKVN;                      // M*H
    ushort* hb     = ctxb + (size_t)M_ * H_;                        // M*FF
    ushort* Wt_qkv = hb + (size_t)M_ * FF_;                         // 2304*768
    ushort* Wt_o   = Wt_qkv + (size_t)QKVN * H_;                    // 768*768
    ushort* Wt_1   = Wt_o + (size_t)H_ * H_;                        // 3072*768
    ushort* Wt_2   = Wt_1 + (size_t)FF_ * H_;                       // 768*3072

    dim3 blk(256);
    dim3 tblk(32, 8);

    embed_ln_kernel<<<M_, blk, 0, stream>>>(input_ids, token_type, word_emb, pos_emb,
                                            type_emb, emb_ln_g, emb_ln_b, x,
                                            (__hip_bfloat16*)xb);

    const dim3 gQKV(QKVN / TN, M_ / TM);   // 18 x 16
    const dim3 gO(H_ / TN, M_ / TM);       //  6 x 16
    const dim3 gF1(FF_ / TN, M_ / TM);     // 24 x 16
    const dim3 gA(S_ / 64, NH_, B_);       //  8 x 12 x 4

    for (int l = 0; l < L_; l++) {
        prep_layer_kernel<<<6921, tblk, 0, stream>>>(
            Wq + (size_t)l * H_ * H_, Wk + (size_t)l * H_ * H_,
            Wv + (size_t)l * H_ * H_, Wo + (size_t)l * H_ * H_,
            W1 + (size_t)l * H_ * FF_, W2 + (size_t)l * FF_ * H_,
            bq + l * H_, bk + l * H_, bv + l * H_,
            Wt_qkv, Wt_o, Wt_1, Wt_2, b_qkv);

        gemm_mfma_kernel<0, 1><<<gQKV, blk, 0, stream>>>(
            xb, Wt_qkv, b_qkv, qkvb, M_, H_, QKVN);

        flash_attn_mfma_kernel<<<gA, blk, 0, stream>>>(
            qkvb, attn_mask, (__hip_bfloat16*)ctxb);

        gemm_mfma_kernel<0, 0><<<gO, blk, 0, stream>>>(
            ctxb, Wt_o, bo + l * H_, tmp768, M_, H_, H_);
        add_ln_kernel<<<M_, blk, 0, stream>>>(x, tmp768, ln1_g + l * H_, ln1_b + l * H_,
                                              (__hip_bfloat16*)xb);

        gemm_mfma_kernel<1, 1><<<gF1, blk, 0, stream>>>(
            xb, Wt_1, b1 + l * FF_, hb, M_, H_, FF_);
        gemm_mfma_kernel<0, 0><<<gO, blk, 0, stream>>>(
            hb, Wt_2, b2 + l * H_, tmp768, M_, FF_, H_);
        add_ln_kernel<<<M_, blk, 0, stream>>>(x, tmp768, ln2_g + l * H_, ln2_b + l * H_,
                                              (__hip_bfloat16*)xb);
    }

    qa_kernel<<<M_, blk, 0, stream>>>(x, qa_w, qa_b, emis);
    crf_parallel_kernel<<<1, 256, 0, stream>>>(emis, attn_mask, start_pos, end_pos,
                                               crf_start, crf_end, crf_trans, out);
}